// Round 5
// baseline (119.357 us; speedup 1.0000x reference)
//
#include <hip/hip_runtime.h>

#define T_PAD   962048   // length of reflect-padded waveform
#define T_RAW   960000
#define NFRM    1879
#define OUTW    1876
#define MEDLEN  1864
#define WINL    30
#define PADL    14
#define NBX     470      // number of frame-group blocks

// ---------------- Kernel 1: NCCF + per-frame lag selection ----------------
// One wave per frame, 4 frames per 256-thread block.
// Lane t (t<48) owns lags 4t+1 .. 4t+4.
// LDS-pipe relief: the wave-uniform A-stream is read from GLOBAL memory
// (L1-resident broadcast) for interior waves; only reflect-touching waves
// read A from LDS. nx stays in LDS (1 ds_read_b128/iter instead of 2).
__global__ __launch_bounds__(256) void nccf_kernel(const float* __restrict__ wav,
                                                   int* __restrict__ idxArr) {
    const int bx   = blockIdx.x;     // frame group (4 frames)
    const int b    = blockIdx.y;     // batch
    const int tid  = threadIdx.x;
    const int wave = tid >> 6;
    const int lane = tid & 63;

    __shared__ __align__(16) float sh[2304];
    __shared__ double Pw1[4][189];   // P[1..189]   -> Pw1[idx-1]
    __shared__ double Pw2[4][190];   // P[512..701] -> Pw2[idx-512]

    const long a0 = (long)bx * 2048;
    const float* wrow = wav + (long)b * T_RAW;

    // Stage wp[a0 .. a0+2237) with on-the-fly reflect pad + zero tail.
    for (int s = tid; s < 2304; s += 256) {
        float v = 0.0f;
        long t = a0 + s;
        if (s < 2237 && t < T_PAD) {
            long u = t - 1024;
            if (u < 0) u = -u;
            if (u >= T_RAW) u = 2L * (T_RAW - 1) - u;
            v = wrow[u];
        }
        sh[s] = v;
    }
    __syncthreads();

    const int frame = bx * 4 + wave;
    const bool fvalid = (frame < NFRM);
    const float* W = sh + (wave << 9);

    // Wave-parallel fp64 prefix-of-squares over W[0..704): 11 elems/lane + scan.
    // Only indices in [1,189] and [512,701] are stored (windowed).
    {
        const float* p = W + lane * 11;
        double part[11];
        double run = 0.0;
        #pragma unroll
        for (int m = 0; m < 11; ++m) { double x = (double)p[m]; run = fma(x, x, run); part[m] = run; }
        double inc = run;
        #pragma unroll
        for (int off = 1; off < 64; off <<= 1) {
            double v = __shfl_up(inc, off);
            if (lane >= off) inc += v;
        }
        double base = inc - run;          // exclusive prefix
        #pragma unroll
        for (int m = 0; m < 11; ++m) {
            int idx = lane * 11 + m + 1;  // 1..704
            double val = base + part[m];
            if (idx <= 189)                 Pw1[wave][idx - 1]   = val;
            else if (idx >= 512 && idx <= 701) Pw2[wave][idx - 512] = val;
        }
    }

    // Main NCCF loop: 4 lags per lane, sliding register window, fp32 accum.
    float f0 = 0.0f, f1 = 0.0f, f2 = 0.0f, f3 = 0.0f;
    const int t = lane;
    if (fvalid && t < 48) {
        const float4* W4 = (const float4*)W;
        float4 cur = W4[t];
        float c1 = cur.y, c2 = cur.z, c3 = cur.w;

        // A-stream source: global (interior waves) or LDS (reflect-touching).
        const bool reflA = (bx == 0 && wave < 2) || (bx == NBX - 1 && wave >= 1);
        if (!reflA) {
            // wp[a0 + 512*wave + j] == wav[b*T_RAW + a0 + 512*wave + j - 1024]
            int wv = __builtin_amdgcn_readfirstlane(wave);
            const float* gA = wrow + (a0 + ((long)wv << 9) - 1024);
            const float4* gA4 = (const float4*)gA;   // 16B-aligned (all terms %4==0)
            #pragma unroll 4
            for (int k = 0; k < 128; ++k) {
                float4 A  = gA4[k];           // wave-uniform VMEM broadcast (L1 hit)
                float4 nx = W4[t + k + 1];    // per-lane LDS, 16B stride
                f0 = fmaf(A.x, c1,   f0); f0 = fmaf(A.y, c2,   f0); f0 = fmaf(A.z, c3,   f0); f0 = fmaf(A.w, nx.x, f0);
                f1 = fmaf(A.x, c2,   f1); f1 = fmaf(A.y, c3,   f1); f1 = fmaf(A.z, nx.x, f1); f1 = fmaf(A.w, nx.y, f1);
                f2 = fmaf(A.x, c3,   f2); f2 = fmaf(A.y, nx.x, f2); f2 = fmaf(A.z, nx.y, f2); f2 = fmaf(A.w, nx.z, f2);
                f3 = fmaf(A.x, nx.x, f3); f3 = fmaf(A.y, nx.y, f3); f3 = fmaf(A.z, nx.z, f3); f3 = fmaf(A.w, nx.w, f3);
                c1 = nx.y; c2 = nx.z; c3 = nx.w;
            }
        } else {
            #pragma unroll 4
            for (int k = 0; k < 128; ++k) {
                float4 A  = W4[k];            // LDS broadcast (reflect data)
                float4 nx = W4[t + k + 1];
                f0 = fmaf(A.x, c1,   f0); f0 = fmaf(A.y, c2,   f0); f0 = fmaf(A.z, c3,   f0); f0 = fmaf(A.w, nx.x, f0);
                f1 = fmaf(A.x, c2,   f1); f1 = fmaf(A.y, c3,   f1); f1 = fmaf(A.z, nx.x, f1); f1 = fmaf(A.w, nx.y, f1);
                f2 = fmaf(A.x, c3,   f2); f2 = fmaf(A.y, nx.x, f2); f2 = fmaf(A.z, nx.y, f2); f2 = fmaf(A.w, nx.z, f2);
                f3 = fmaf(A.x, nx.x, f3); f3 = fmaf(A.y, nx.y, f3); f3 = fmaf(A.z, nx.z, f3); f3 = fmaf(A.w, nx.w, f3);
                c1 = nx.y; c2 = nx.z; c3 = nx.w;
            }
        }
    }

    // Per-lane nccf + candidate (max, argmax) pairs; fp64 compares (np-like).
    double bestv = -1e300, halfv = -1e300;
    int bestk = 1 << 30, halfk = 1 << 30;
    if (fvalid && t < 48) {
        double s1 = 1e-9 + sqrt(Pw2[wave][0]);             // frame norm: P[512]
        double s1n = s1 * s1;
        double accs[4] = {(double)f0, (double)f1, (double)f2, (double)f3};
        #pragma unroll
        for (int r = 0; r < 4; ++r) {
            int lag  = 4 * t + 1 + r;
            int kidx = lag - 1;                             // nccf lag index
            if (kidx <= 188) {
                double q = Pw2[wave][lag] - Pw1[wave][lag - 1];  // P[lag+512]-P[lag]
                double s2 = 1e-9 + sqrt(q);
                double s2n = s2 * s2;
                double v = accs[r] / s1n / s2n;
                if (kidx >= 5) {
                    if (v > bestv || (v == bestv && kidx < bestk)) { bestv = v; bestk = kidx; }
                    if (kidx <= 93 && (v > halfv || (v == halfv && kidx < halfk))) { halfv = v; halfk = kidx; }
                }
            }
        }
    }

    // Wave-wide (max, first-argmax) reduction for both slices.
    #pragma unroll
    for (int off = 32; off >= 1; off >>= 1) {
        double ov = __shfl_xor(bestv, off); int ok = __shfl_xor(bestk, off);
        if (ov > bestv || (ov == bestv && ok < bestk)) { bestv = ov; bestk = ok; }
        double hv = __shfl_xor(halfv, off); int hk = __shfl_xor(halfk, off);
        if (hv > halfv || (hv == halfv && hk < halfk)) { halfv = hv; halfk = hk; }
    }

    if (fvalid && lane == 0) {
        bool m = (halfv > 0.99 * bestv);
        int sel = m ? halfk : bestk;
        idxArr[b * NFRM + frame] = sel + 1;                 // = chosen lag
    }
}

// ---------------- Kernel 2: 30-wide median filter + pitch ----------------
__global__ __launch_bounds__(256) void med_kernel(const int* __restrict__ idxArr,
                                                  float* __restrict__ out) {
    int gid = blockIdx.x * 256 + threadIdx.x;
    if (gid >= 8 * OUTW) return;
    int b = gid / OUTW;
    int i = gid - b * OUTW;
    float o = 0.0f;
    if (i < MEDLEN) {
        const int* row = idxArr + b * NFRM;
        int vals[WINL];
        #pragma unroll
        for (int m = 0; m < WINL; ++m) {
            int s = i + m - PADL;                           // left pad = repeat idx[0]
            vals[m] = row[s < 0 ? 0 : s];
        }
        int med = vals[0];
        #pragma unroll
        for (int c = 0; c < WINL; ++c) {
            int cl = 0, ce = 0;
            #pragma unroll
            for (int m = 0; m < WINL; ++m) {
                cl += (vals[m] <  vals[c]) ? 1 : 0;
                ce += (vals[m] == vals[c]) ? 1 : 0;
            }
            if (cl <= 14 && 14 < cl + ce) med = vals[c];    // rank-14 = sorted[14]
        }
        o = 16000.0f / (1e-9f + (float)med);
    }
    out[gid] = o;
}

extern "C" void kernel_launch(void* const* d_in, const int* in_sizes, int n_in,
                              void* d_out, int out_size, void* d_ws, size_t ws_size,
                              hipStream_t stream) {
    const float* wav = (const float*)d_in[0];
    float* out = (float*)d_out;
    int* idxArr = (int*)d_ws;                               // 8*1879 ints = 60128 B

    dim3 gB(NBX, 8);                                        // 470 x 8 blocks
    hipLaunchKernelGGL(nccf_kernel, gB, dim3(256), 0, stream, wav, idxArr);

    int total = 8 * OUTW;
    hipLaunchKernelGGL(med_kernel, dim3((total + 255) / 256), dim3(256), 0, stream,
                       idxArr, out);
}

// Round 6
// 99.514 us; speedup vs baseline: 1.1994x; 1.1994x over previous
//
#include <hip/hip_runtime.h>

#define T_PAD   962048   // length of reflect-padded waveform
#define T_RAW   960000
#define NFRM    1879
#define OUTW    1876
#define MEDLEN  1864
#define WINL    30
#define PADL    14
#define NBX     470      // number of frame-group blocks

__device__ __forceinline__ float rfl(float x) {
    return __uint_as_float(__builtin_amdgcn_readfirstlane(__float_as_uint(x)));
}

// ---------------- Kernel 1: NCCF + per-frame lag selection ----------------
// One wave per frame, 4 frames per 256-thread block.
// Lane t (t<48) owns lags 4t+1 .. 4t+4.
// LDS-pipe relief: the wave-uniform A-stream is NOT re-read from LDS; it is
// recovered from lane 0's nx register of the previous iteration via
// v_readfirstlane (VALU->SGPR broadcast, no memory pipe at all).
// fp32 inner dot products; fp64 windowed prefix-of-squares norms; fp64 compares.
__global__ __launch_bounds__(256) void nccf_kernel(const float* __restrict__ wav,
                                                   int* __restrict__ idxArr) {
    const int bx   = blockIdx.x;     // frame group (4 frames)
    const int b    = blockIdx.y;     // batch
    const int tid  = threadIdx.x;
    const int wave = tid >> 6;
    const int lane = tid & 63;

    __shared__ __align__(16) float sh[2304];
    __shared__ double Pw1[4][189];   // P[1..189]   -> Pw1[idx-1]
    __shared__ double Pw2[4][190];   // P[512..701] -> Pw2[idx-512]

    const long a0 = (long)bx * 2048;
    const float* wrow = wav + (long)b * T_RAW;

    // Stage wp[a0 .. a0+2237) with on-the-fly reflect pad + zero tail.
    for (int s = tid; s < 2304; s += 256) {
        float v = 0.0f;
        long t = a0 + s;
        if (s < 2237 && t < T_PAD) {
            long u = t - 1024;
            if (u < 0) u = -u;
            if (u >= T_RAW) u = 2L * (T_RAW - 1) - u;
            v = wrow[u];
        }
        sh[s] = v;
    }
    __syncthreads();

    const int frame = bx * 4 + wave;
    const bool fvalid = (frame < NFRM);
    const float* W = sh + (wave << 9);

    // Wave-parallel fp64 prefix-of-squares over W[0..704): 11 elems/lane + scan.
    // Only indices in [1,189] and [512,701] are stored (windowed).
    {
        const float* p = W + lane * 11;
        double part[11];
        double run = 0.0;
        #pragma unroll
        for (int m = 0; m < 11; ++m) { double x = (double)p[m]; run = fma(x, x, run); part[m] = run; }
        double inc = run;
        #pragma unroll
        for (int off = 1; off < 64; off <<= 1) {
            double v = __shfl_up(inc, off);
            if (lane >= off) inc += v;
        }
        double base = inc - run;          // exclusive prefix
        #pragma unroll
        for (int m = 0; m < 11; ++m) {
            int idx = lane * 11 + m + 1;  // 1..704
            double val = base + part[m];
            if (idx <= 189)                 Pw1[wave][idx - 1]   = val;
            else if (idx >= 512 && idx <= 701) Pw2[wave][idx - 512] = val;
        }
    }

    // Main NCCF loop: 4 lags per lane, sliding register window, fp32 accum.
    float f0 = 0.0f, f1 = 0.0f, f2 = 0.0f, f3 = 0.0f;
    const int t = lane;
    if (fvalid && t < 48) {
        const float4* W4 = (const float4*)W;
        float4 cur = W4[t];
        float c1 = cur.y, c2 = cur.z, c3 = cur.w;
        // A for iteration 0 = W4[0] = lane 0's cur.
        float A0 = rfl(cur.x), A1 = rfl(cur.y), A2 = rfl(cur.z), A3 = rfl(cur.w);
        #pragma unroll 4
        for (int k = 0; k < 128; ++k) {
            float4 nx = W4[t + k + 1];    // per-lane LDS, 16B stride (only LDS op)
            f0 = fmaf(A0, c1,   f0); f0 = fmaf(A1, c2,   f0); f0 = fmaf(A2, c3,   f0); f0 = fmaf(A3, nx.x, f0);
            f1 = fmaf(A0, c2,   f1); f1 = fmaf(A1, c3,   f1); f1 = fmaf(A2, nx.x, f1); f1 = fmaf(A3, nx.y, f1);
            f2 = fmaf(A0, c3,   f2); f2 = fmaf(A1, nx.x, f2); f2 = fmaf(A2, nx.y, f2); f2 = fmaf(A3, nx.z, f2);
            f3 = fmaf(A0, nx.x, f3); f3 = fmaf(A1, nx.y, f3); f3 = fmaf(A2, nx.z, f3); f3 = fmaf(A3, nx.w, f3);
            // A for next iteration = W4[k+1] = lane 0's nx.
            A0 = rfl(nx.x); A1 = rfl(nx.y); A2 = rfl(nx.z); A3 = rfl(nx.w);
            c1 = nx.y; c2 = nx.z; c3 = nx.w;
        }
    }

    // Per-lane nccf + candidate (max, argmax) pairs; fp64 compares (np-like).
    double bestv = -1e300, halfv = -1e300;
    int bestk = 1 << 30, halfk = 1 << 30;
    if (fvalid && t < 48) {
        double s1 = 1e-9 + sqrt(Pw2[wave][0]);             // frame norm: P[512]
        double s1n = s1 * s1;
        double accs[4] = {(double)f0, (double)f1, (double)f2, (double)f3};
        #pragma unroll
        for (int r = 0; r < 4; ++r) {
            int lag  = 4 * t + 1 + r;
            int kidx = lag - 1;                             // nccf lag index
            if (kidx <= 188) {
                double q = Pw2[wave][lag] - Pw1[wave][lag - 1];  // P[lag+512]-P[lag]
                double s2 = 1e-9 + sqrt(q);
                double s2n = s2 * s2;
                double v = accs[r] / s1n / s2n;
                if (kidx >= 5) {
                    if (v > bestv || (v == bestv && kidx < bestk)) { bestv = v; bestk = kidx; }
                    if (kidx <= 93 && (v > halfv || (v == halfv && kidx < halfk))) { halfv = v; halfk = kidx; }
                }
            }
        }
    }

    // Wave-wide (max, first-argmax) reduction for both slices.
    #pragma unroll
    for (int off = 32; off >= 1; off >>= 1) {
        double ov = __shfl_xor(bestv, off); int ok = __shfl_xor(bestk, off);
        if (ov > bestv || (ov == bestv && ok < bestk)) { bestv = ov; bestk = ok; }
        double hv = __shfl_xor(halfv, off); int hk = __shfl_xor(halfk, off);
        if (hv > halfv || (hv == halfv && hk < halfk)) { halfv = hv; halfk = hk; }
    }

    if (fvalid && lane == 0) {
        bool m = (halfv > 0.99 * bestv);
        int sel = m ? halfk : bestk;
        idxArr[b * NFRM + frame] = sel + 1;                 // = chosen lag
    }
}

// ---------------- Kernel 2: 30-wide median filter + pitch ----------------
__global__ __launch_bounds__(256) void med_kernel(const int* __restrict__ idxArr,
                                                  float* __restrict__ out) {
    int gid = blockIdx.x * 256 + threadIdx.x;
    if (gid >= 8 * OUTW) return;
    int b = gid / OUTW;
    int i = gid - b * OUTW;
    float o = 0.0f;
    if (i < MEDLEN) {
        const int* row = idxArr + b * NFRM;
        int vals[WINL];
        #pragma unroll
        for (int m = 0; m < WINL; ++m) {
            int s = i + m - PADL;                           // left pad = repeat idx[0]
            vals[m] = row[s < 0 ? 0 : s];
        }
        int med = vals[0];
        #pragma unroll
        for (int c = 0; c < WINL; ++c) {
            int cl = 0, ce = 0;
            #pragma unroll
            for (int m = 0; m < WINL; ++m) {
                cl += (vals[m] <  vals[c]) ? 1 : 0;
                ce += (vals[m] == vals[c]) ? 1 : 0;
            }
            if (cl <= 14 && 14 < cl + ce) med = vals[c];    // rank-14 = sorted[14]
        }
        o = 16000.0f / (1e-9f + (float)med);
    }
    out[gid] = o;
}

extern "C" void kernel_launch(void* const* d_in, const int* in_sizes, int n_in,
                              void* d_out, int out_size, void* d_ws, size_t ws_size,
                              hipStream_t stream) {
    const float* wav = (const float*)d_in[0];
    float* out = (float*)d_out;
    int* idxArr = (int*)d_ws;                               // 8*1879 ints = 60128 B

    dim3 gB(NBX, 8);                                        // 470 x 8 blocks
    hipLaunchKernelGGL(nccf_kernel, gB, dim3(256), 0, stream, wav, idxArr);

    int total = 8 * OUTW;
    hipLaunchKernelGGL(med_kernel, dim3((total + 255) / 256), dim3(256), 0, stream,
                       idxArr, out);
}

// Round 7
// 73.858 us; speedup vs baseline: 1.6160x; 1.3474x over previous
//
#include <hip/hip_runtime.h>

#define T_WPAD  962048   // reflect-padded waveform length (before zero tail)
#define T_RAW   960000
#define NFRM    1879
#define OUTW    1876
#define MEDLEN  1864
#define WINL    30
#define PADL    14
#define FPB     8        // frames per block
#define NBX     235      // ceil(NFRM / FPB)
#define XLEN    4296     // 7*512 + 705 + pad: block's signal window

// ---------------- Kernel 1: NCCF + per-frame lag selection ----------------
// 256 thr = 4 waves; each wave handles TWO frames (one per 32-lane half).
// Lane: h = lane>>5 selects frame, s = lane&31 owns lags 6s+1..6s+6.
// Per k-iter (4 j-steps): 1 ds_read_b128 A (2-addr broadcast) + 2 ds_read_b64
// nx + 24 fp32 FMA -> per frame: 12 FMA-instr + 1.5 LDS-instr (vs 16+2 in R4).
// Norms: fp64 half-wave prefix scan, windows stored fp32 (error ~8e-8 rel).
__global__ __launch_bounds__(256) void nccf_kernel(const float* __restrict__ wav,
                                                   int* __restrict__ idxArr) {
    const int bx   = blockIdx.x;
    const int b    = blockIdx.y;
    const int tid  = threadIdx.x;
    const int wave = tid >> 6;
    const int lane = tid & 63;
    const int h    = lane >> 5;
    const int s    = lane & 31;

    __shared__ __align__(16) float X[XLEN];
    __shared__ float Pw1[FPB][190];   // P[1..189]   -> Pw1[F][idx-1]
    __shared__ float Pw2[FPB][190];   // P[512..701] -> Pw2[F][idx-512]

    const long a0 = (long)bx * (FPB * 512);
    const float* wrow = wav + (long)b * T_RAW;

    // Stage wp[a0 .. a0+XLEN) with on-the-fly reflect pad + zero tail.
    for (int i = tid; i < XLEN; i += 256) {
        float v = 0.0f;
        long t = a0 + i;
        if (t < T_WPAD) {
            long u = t - 1024;
            if (u < 0) u = -u;
            if (u >= T_RAW) u = 2L * (T_RAW - 1) - u;
            v = wrow[u];
        }
        X[i] = v;
    }
    __syncthreads();

    const int F = wave * 2 + h;          // frame index within block (0..7)
    const int g = bx * FPB + F;          // global frame
    const bool valid = (g < NFRM);
    const float* Xf = X + F * 512;

    // Half-wave fp64 prefix-of-squares over Xf[0..703]; store fp32 windows.
    // Two passes to keep VGPR pressure low (no part[22] array).
    {
        const float* p = Xf + s * 22;
        double run = 0.0;
        #pragma unroll
        for (int m = 0; m < 22; ++m) { double x = (double)p[m]; run = fma(x, x, run); }
        double inc = run;
        #pragma unroll
        for (int off = 1; off < 32; off <<= 1) {
            double v = __shfl_up(inc, off, 32);
            if (s >= off) inc += v;
        }
        double run2 = inc - run;          // exclusive prefix for this lane
        #pragma unroll
        for (int m = 0; m < 22; ++m) {
            double x = (double)p[m];
            run2 = fma(x, x, run2);
            int idx = s * 22 + m + 1;     // 1..704
            float val = (float)run2;
            if (idx <= 189)                     Pw1[F][idx - 1]   = val;
            else if (idx >= 512 && idx <= 701)  Pw2[F][idx - 512] = val;
        }
    }
    // Pw[F] written and read only by this same half-wave; LDS ops from one
    // wave are in-order -> no barrier needed.

    // Main loop: sliding 12-float register window, 6 lags/lane, fp32 accum.
    float acc[6] = {0.f, 0.f, 0.f, 0.f, 0.f, 0.f};
    {
        const float2* X2 = (const float2*)X;
        const int base2 = (F * 512 + 6 * s) >> 1;   // float2 index of w[0]
        float w[12];
        #pragma unroll
        for (int d = 0; d < 6; ++d) {
            float2 t2 = X2[base2 + d];
            w[2 * d] = t2.x; w[2 * d + 1] = t2.y;
        }
        const float4* A4 = (const float4*)(X + F * 512);
        #pragma unroll 4
        for (int k = 0; k < 127; ++k) {
            float4 Av = A4[k];                       // per-half uniform broadcast
            #pragma unroll
            for (int r = 0; r < 6; ++r) {
                acc[r] = fmaf(Av.x, w[1 + r], acc[r]);
                acc[r] = fmaf(Av.y, w[2 + r], acc[r]);
                acc[r] = fmaf(Av.z, w[3 + r], acc[r]);
                acc[r] = fmaf(Av.w, w[4 + r], acc[r]);
            }
            float2 n0 = X2[base2 + 2 * k + 6];       // Xf[6s+4k+12..13]
            float2 n1 = X2[base2 + 2 * k + 7];       // Xf[6s+4k+14..15]
            #pragma unroll
            for (int i = 0; i < 8; ++i) w[i] = w[i + 4];
            w[8] = n0.x; w[9] = n0.y; w[10] = n1.x; w[11] = n1.y;
        }
        {   // last iteration, no prefetch
            float4 Av = A4[127];
            #pragma unroll
            for (int r = 0; r < 6; ++r) {
                acc[r] = fmaf(Av.x, w[1 + r], acc[r]);
                acc[r] = fmaf(Av.y, w[2 + r], acc[r]);
                acc[r] = fmaf(Av.z, w[3 + r], acc[r]);
                acc[r] = fmaf(Av.w, w[4 + r], acc[r]);
            }
        }
    }

    // Per-lane selection over its 6 lags (fp32, np-like first-max ties).
    float bestv = -1e30f, halfv = -1e30f;
    int bestk = 1 << 30, halfk = 1 << 30;
    {
        float s1 = 1e-9f + sqrtf(Pw2[F][0]);        // frame norm: P[512]
        float s1n = s1 * s1;
        #pragma unroll
        for (int r = 0; r < 6; ++r) {
            int lag  = 6 * s + 1 + r;
            int kidx = lag - 1;                      // nccf lag index 0..191
            if (kidx <= 188) {
                float q  = Pw2[F][lag] - Pw1[F][lag - 1];   // P[lag+512]-P[lag]
                float s2 = 1e-9f + sqrtf(q);
                float v  = acc[r] / s1n / (s2 * s2);
                if (kidx >= 5) {
                    if (v > bestv) { bestv = v; bestk = kidx; }
                    if (kidx <= 93 && v > halfv) { halfv = v; halfk = kidx; }
                }
            }
        }
    }

    // Half-wave (max, first-argmax) reduction for both slices (width 32).
    #pragma unroll
    for (int off = 16; off >= 1; off >>= 1) {
        float ov = __shfl_xor(bestv, off, 32); int ok = __shfl_xor(bestk, off, 32);
        if (ov > bestv || (ov == bestv && ok < bestk)) { bestv = ov; bestk = ok; }
        float hv = __shfl_xor(halfv, off, 32); int hk = __shfl_xor(halfk, off, 32);
        if (hv > halfv || (hv == halfv && hk < halfk)) { halfv = hv; halfk = hk; }
    }

    if (valid && s == 0) {
        bool m = (halfv > 0.99f * bestv);
        int sel = m ? halfk : bestk;
        idxArr[b * NFRM + g] = sel + 1;              // = chosen lag
    }
}

// ---------------- Kernel 2: 30-wide median filter + pitch ----------------
__global__ __launch_bounds__(256) void med_kernel(const int* __restrict__ idxArr,
                                                  float* __restrict__ out) {
    int gid = blockIdx.x * 256 + threadIdx.x;
    if (gid >= 8 * OUTW) return;
    int b = gid / OUTW;
    int i = gid - b * OUTW;
    float o = 0.0f;
    if (i < MEDLEN) {
        const int* row = idxArr + b * NFRM;
        int vals[WINL];
        #pragma unroll
        for (int m = 0; m < WINL; ++m) {
            int sIdx = i + m - PADL;                 // left pad = repeat idx[0]
            vals[m] = row[sIdx < 0 ? 0 : sIdx];
        }
        int med = vals[0];
        #pragma unroll
        for (int c = 0; c < WINL; ++c) {
            int cl = 0, ce = 0;
            #pragma unroll
            for (int m = 0; m < WINL; ++m) {
                cl += (vals[m] <  vals[c]) ? 1 : 0;
                ce += (vals[m] == vals[c]) ? 1 : 0;
            }
            if (cl <= 14 && 14 < cl + ce) med = vals[c];   // rank-14 = sorted[14]
        }
        o = 16000.0f / (1e-9f + (float)med);
    }
    out[gid] = o;
}

extern "C" void kernel_launch(void* const* d_in, const int* in_sizes, int n_in,
                              void* d_out, int out_size, void* d_ws, size_t ws_size,
                              hipStream_t stream) {
    const float* wav = (const float*)d_in[0];
    float* out = (float*)d_out;
    int* idxArr = (int*)d_ws;                        // 8*1879 ints = 60128 B

    dim3 gB(NBX, 8);                                 // 235 x 8 blocks, 8 frames each
    hipLaunchKernelGGL(nccf_kernel, gB, dim3(256), 0, stream, wav, idxArr);

    int total = 8 * OUTW;
    hipLaunchKernelGGL(med_kernel, dim3((total + 255) / 256), dim3(256), 0, stream,
                       idxArr, out);
}

// Round 8
// 72.005 us; speedup vs baseline: 1.6576x; 1.0257x over previous
//
#include <hip/hip_runtime.h>

#define T_WPAD  962048   // reflect-padded waveform length (before zero tail)
#define T_RAW   960000
#define NFRM    1879
#define OUTW    1876
#define MEDLEN  1864
#define WINL    30
#define PADL    14
#define FPB     16       // frames per block
#define NBX     118      // ceil(NFRM / FPB)
#define XLEN    8392     // 15*512 + 705 + pad (float4-divisible)
#define X4LEN   2098

// ---------------- Kernel 1: NCCF + per-frame lag selection ----------------
// 256 thr = 4 waves; each wave handles FOUR frames (one per 16-lane group).
// Lane: g = lane>>4 selects frame-in-wave, s = lane&15 owns lags 12s+1..12s+12.
// Window base 12s is float4-aligned for every lane -> per 4 j-steps the wave
// issues 1 ds_read_b128 (A, 4-addr group-broadcast) + 1 ds_read_b128 (window
// advance) = 2 LDS instrs for 4 frames x 4 steps x 12 lags (48 FMA instrs).
// fp32 inner products; fp64 prefix-of-squares scan stored as fp32 windows.
__global__ __launch_bounds__(256) void nccf_kernel(const float* __restrict__ wav,
                                                   int* __restrict__ idxArr) {
    const int bx   = blockIdx.x;
    const int b    = blockIdx.y;
    const int tid  = threadIdx.x;
    const int wave = tid >> 6;
    const int lane = tid & 63;
    const int g    = lane >> 4;          // frame within wave (0..3)
    const int s    = lane & 15;          // lag-group lane (0..15)

    __shared__ __align__(16) float X[XLEN];
    __shared__ float Pw1[FPB][190];      // P[1..189]   -> Pw1[F][idx-1]
    __shared__ float Pw2[FPB][190];      // P[512..701] -> Pw2[F][idx-512]

    const long a0 = (long)bx * (FPB * 512);
    const float* wrow = wav + (long)b * T_RAW;

    // Stage wp[a0 .. a0+XLEN): vectorized fast path for interior blocks.
    if (bx >= 1 && bx <= NBX - 2) {
        const float4* src = (const float4*)(wrow + (a0 - 1024));
        float4* dst = (float4*)X;
        for (int i = tid; i < X4LEN; i += 256) dst[i] = src[i];
    } else {
        for (int i = tid; i < XLEN; i += 256) {
            float v = 0.0f;
            long t = a0 + i;
            if (t < T_WPAD) {
                long u = t - 1024;
                if (u < 0) u = -u;
                if (u >= T_RAW) u = 2L * (T_RAW - 1) - u;
                v = wrow[u];
            }
            X[i] = v;
        }
    }
    __syncthreads();

    const int F  = wave * 4 + g;         // frame within block (0..15)
    const int gf = bx * FPB + F;         // global frame
    const bool valid = (gf < NFRM);
    const float* Xf = X + F * 512;

    // Per-frame fp64 prefix-of-squares over Xf[0..703] by its 16-lane group:
    // 44 elems/lane, two passes; windows stored fp32.
    {
        const float* p = Xf + s * 44;
        double run = 0.0;
        #pragma unroll
        for (int m = 0; m < 44; ++m) { double x = (double)p[m]; run = fma(x, x, run); }
        double inc = run;
        #pragma unroll
        for (int off = 1; off < 16; off <<= 1) {
            double v = __shfl_up(inc, off, 16);
            if (s >= off) inc += v;
        }
        double run2 = inc - run;          // exclusive prefix for this lane
        #pragma unroll
        for (int m = 0; m < 44; ++m) {
            double x = (double)p[m];
            run2 = fma(x, x, run2);
            int idx = s * 44 + m + 1;     // 1..704
            float val = (float)run2;
            if (idx <= 189)                     Pw1[F][idx - 1]   = val;
            else if (idx >= 512 && idx <= 701)  Pw2[F][idx - 512] = val;
        }
    }
    // Pw[F] written and read only by this same 16-lane group; same-wave LDS
    // ops are in-order -> no barrier needed.

    // Main loop: 16-float register window, 12 lags/lane, fp32 accum.
    float acc[12];
    #pragma unroll
    for (int r = 0; r < 12; ++r) acc[r] = 0.0f;
    {
        const float4* X4 = (const float4*)X;
        const int aBase = F * 128;            // float4 index of Xf[0]
        const int wBase = aBase + 3 * s;      // float4 index of Xf[12s]
        float w[16];
        #pragma unroll
        for (int d = 0; d < 4; ++d) {
            float4 t4 = X4[wBase + d];
            w[4 * d] = t4.x; w[4 * d + 1] = t4.y; w[4 * d + 2] = t4.z; w[4 * d + 3] = t4.w;
        }
        float4 A = X4[aBase];
        #pragma unroll 4
        for (int k = 0; k < 127; ++k) {
            float4 An = X4[aBase + k + 1];    // next A (group-broadcast)
            float4 nx = X4[wBase + k + 4];    // window advance (aligned b128)
            #pragma unroll
            for (int r = 0; r < 12; ++r) {
                acc[r] = fmaf(A.x, w[r + 1], acc[r]);
                acc[r] = fmaf(A.y, w[r + 2], acc[r]);
                acc[r] = fmaf(A.z, w[r + 3], acc[r]);
                acc[r] = fmaf(A.w, w[r + 4], acc[r]);
            }
            #pragma unroll
            for (int i = 0; i < 12; ++i) w[i] = w[i + 4];
            w[12] = nx.x; w[13] = nx.y; w[14] = nx.z; w[15] = nx.w;
            A = An;
        }
        #pragma unroll
        for (int r = 0; r < 12; ++r) {        // last iteration, no prefetch
            acc[r] = fmaf(A.x, w[r + 1], acc[r]);
            acc[r] = fmaf(A.y, w[r + 2], acc[r]);
            acc[r] = fmaf(A.z, w[r + 3], acc[r]);
            acc[r] = fmaf(A.w, w[r + 4], acc[r]);
        }
    }

    // Per-lane selection over its 12 lags (fp32, np-like first-max ties).
    float bestv = -1e30f, halfv = -1e30f;
    int bestk = 1 << 30, halfk = 1 << 30;
    {
        float s1 = 1e-9f + sqrtf(Pw2[F][0]);  // frame norm: P[512]
        float s1n = s1 * s1;
        #pragma unroll
        for (int r = 1; r <= 12; ++r) {
            int lag  = 12 * s + r;
            int kidx = lag - 1;               // nccf lag index 0..191
            if (kidx <= 188) {
                float q  = Pw2[F][lag] - Pw1[F][lag - 1];  // P[lag+512]-P[lag]
                float s2 = 1e-9f + sqrtf(q);
                float v  = acc[r - 1] / s1n / (s2 * s2);
                if (kidx >= 5) {
                    if (v > bestv) { bestv = v; bestk = kidx; }
                    if (kidx <= 93 && v > halfv) { halfv = v; halfk = kidx; }
                }
            }
        }
    }

    // 16-lane (max, first-argmax) reduction for both slices.
    #pragma unroll
    for (int off = 8; off >= 1; off >>= 1) {
        float ov = __shfl_xor(bestv, off, 16); int ok = __shfl_xor(bestk, off, 16);
        if (ov > bestv || (ov == bestv && ok < bestk)) { bestv = ov; bestk = ok; }
        float hv = __shfl_xor(halfv, off, 16); int hk = __shfl_xor(halfk, off, 16);
        if (hv > halfv || (hv == halfv && hk < halfk)) { halfv = hv; halfk = hk; }
    }

    if (valid && s == 0) {
        bool m = (halfv > 0.99f * bestv);
        int sel = m ? halfk : bestk;
        idxArr[b * NFRM + gf] = sel + 1;      // = chosen lag
    }
}

// ---------------- Kernel 2: 30-wide median filter + pitch ----------------
__global__ __launch_bounds__(256) void med_kernel(const int* __restrict__ idxArr,
                                                  float* __restrict__ out) {
    int gid = blockIdx.x * 256 + threadIdx.x;
    if (gid >= 8 * OUTW) return;
    int b = gid / OUTW;
    int i = gid - b * OUTW;
    float o = 0.0f;
    if (i < MEDLEN) {
        const int* row = idxArr + b * NFRM;
        int vals[WINL];
        #pragma unroll
        for (int m = 0; m < WINL; ++m) {
            int sIdx = i + m - PADL;          // left pad = repeat idx[0]
            vals[m] = row[sIdx < 0 ? 0 : sIdx];
        }
        int med = vals[0];
        #pragma unroll
        for (int c = 0; c < WINL; ++c) {
            int cl = 0, ce = 0;
            #pragma unroll
            for (int m = 0; m < WINL; ++m) {
                cl += (vals[m] <  vals[c]) ? 1 : 0;
                ce += (vals[m] == vals[c]) ? 1 : 0;
            }
            if (cl <= 14 && 14 < cl + ce) med = vals[c];   // rank-14 = sorted[14]
        }
        o = 16000.0f / (1e-9f + (float)med);
    }
    out[gid] = o;
}

extern "C" void kernel_launch(void* const* d_in, const int* in_sizes, int n_in,
                              void* d_out, int out_size, void* d_ws, size_t ws_size,
                              hipStream_t stream) {
    const float* wav = (const float*)d_in[0];
    float* out = (float*)d_out;
    int* idxArr = (int*)d_ws;                 // 8*1879 ints = 60128 B

    dim3 gB(NBX, 8);                          // 118 x 8 blocks, 16 frames each
    hipLaunchKernelGGL(nccf_kernel, gB, dim3(256), 0, stream, wav, idxArr);

    int total = 8 * OUTW;
    hipLaunchKernelGGL(med_kernel, dim3((total + 255) / 256), dim3(256), 0, stream,
                       idxArr, out);
}

// Round 9
// 66.761 us; speedup vs baseline: 1.7878x; 1.0785x over previous
//
#include <hip/hip_runtime.h>

#define T_WPAD  962048   // reflect-padded waveform length (before zero tail)
#define T_RAW   960000
#define NFRM    1879
#define OUTW    1876
#define MEDLEN  1864
#define WINL    30
#define PADL    14
#define FPB     16       // frames per block
#define NBX     118      // ceil(NFRM / FPB)
#define XLEN    8392     // 15*512 + 705 + pad (float4-divisible)
#define X4LEN   2098

// ---------------- Kernel 1: NCCF + per-frame lag selection ----------------
// 256 thr = 4 waves; each wave handles FOUR frames (one per 16-lane group).
// g = lane>>4 picks frame-in-wave, s = lane&15 owns lags 12s+1..12s+12.
// Per 4 j-steps the wave issues 2 ds_read_b128 (A broadcast + window advance)
// for 16 frame-steps (48 FMA instrs). Norms are computed IN-STREAM: f64
// running sum of fp32 quad-squares of the window stream; no LDS norm arrays,
// no scan phase. LDS = signal tile only (33.6 KB -> 4 blocks/CU).
__global__ __launch_bounds__(256) void nccf_kernel(const float* __restrict__ wav,
                                                   int* __restrict__ idxArr) {
    const int bx   = blockIdx.x;
    const int b    = blockIdx.y;
    const int tid  = threadIdx.x;
    const int wave = tid >> 6;
    const int lane = tid & 63;
    const int g    = lane >> 4;          // frame within wave (0..3)
    const int s    = lane & 15;          // lag-group lane (0..15)

    __shared__ __align__(16) float X[XLEN];

    const long a0 = (long)bx * (FPB * 512);
    const float* wrow = wav + (long)b * T_RAW;

    // Stage wp[a0 .. a0+XLEN): vectorized fast path for interior blocks.
    if (bx >= 1 && bx <= NBX - 2) {
        const float4* src = (const float4*)(wrow + (a0 - 1024));
        float4* dst = (float4*)X;
        for (int i = tid; i < X4LEN; i += 256) dst[i] = src[i];
    } else {
        for (int i = tid; i < XLEN; i += 256) {
            float v = 0.0f;
            long t = a0 + i;
            if (t < T_WPAD) {
                long u = t - 1024;
                if (u < 0) u = -u;
                if (u >= T_RAW) u = 2L * (T_RAW - 1) - u;
                v = wrow[u];
            }
            X[i] = v;
        }
    }
    __syncthreads();

    const int F  = wave * 4 + g;         // frame within block (0..15)
    const int gf = bx * FPB + F;         // global frame
    const bool valid = (gf < NFRM);

    // Main loop: 16-float register window, 12 lags/lane, fp32 dot accum,
    // f64 in-stream sumsq tracking.
    float acc[12];
    #pragma unroll
    for (int r = 0; r < 12; ++r) acc[r] = 0.0f;
    float sq[12];                         // squares of e_0..e_11 (X[12s+j]^2)
    double Tcur = 0.0;                    // running sumsq of lane's stream
    double T512 = 0.0;                    // T(512) = sumsq X[12s .. 12s+512)
    float w[16];

    {
        const float4* X4 = (const float4*)X;
        const int aBase = F * 128;            // float4 index of Xf[0]
        const int wBase = aBase + 3 * s;      // float4 index of Xf[12s]
        #pragma unroll
        for (int d = 0; d < 4; ++d) {
            float4 t4 = X4[wBase + d];
            w[4 * d] = t4.x; w[4 * d + 1] = t4.y; w[4 * d + 2] = t4.z; w[4 * d + 3] = t4.w;
        }
        #pragma unroll
        for (int j = 0; j < 12; ++j) sq[j] = w[j] * w[j];
        // Tcur = T(16): f64 accumulation of the 16 initial squares.
        #pragma unroll
        for (int j = 0; j < 16; ++j) Tcur += (double)(w[j] * w[j]);

        float4 A = X4[aBase];
        // Phase 1: k = 0..123 with T tracking. After iter k, Tcur = T(4k+20).
        #pragma unroll 4
        for (int k = 0; k < 124; ++k) {
            float4 An = X4[aBase + k + 1];    // next A (group-broadcast)
            float4 nx = X4[wBase + k + 4];    // window advance (aligned b128)
            #pragma unroll
            for (int r = 0; r < 12; ++r) {
                acc[r] = fmaf(A.x, w[r + 1], acc[r]);
                acc[r] = fmaf(A.y, w[r + 2], acc[r]);
                acc[r] = fmaf(A.z, w[r + 3], acc[r]);
                acc[r] = fmaf(A.w, w[r + 4], acc[r]);
            }
            float quad = fmaf(nx.x, nx.x, fmaf(nx.y, nx.y, fmaf(nx.z, nx.z, nx.w * nx.w)));
            Tcur += (double)quad;
            #pragma unroll
            for (int i = 0; i < 12; ++i) w[i] = w[i + 4];
            w[12] = nx.x; w[13] = nx.y; w[14] = nx.z; w[15] = nx.w;
            A = An;
        }
        T512 = Tcur;                          // T(512)
        // Phase 2: k = 124..126, no T tracking.
        #pragma unroll
        for (int k = 124; k < 127; ++k) {
            float4 An = X4[aBase + k + 1];
            float4 nx = X4[wBase + k + 4];
            #pragma unroll
            for (int r = 0; r < 12; ++r) {
                acc[r] = fmaf(A.x, w[r + 1], acc[r]);
                acc[r] = fmaf(A.y, w[r + 2], acc[r]);
                acc[r] = fmaf(A.z, w[r + 3], acc[r]);
                acc[r] = fmaf(A.w, w[r + 4], acc[r]);
            }
            #pragma unroll
            for (int i = 0; i < 12; ++i) w[i] = w[i + 4];
            w[12] = nx.x; w[13] = nx.y; w[14] = nx.z; w[15] = nx.w;
            A = An;
        }
        #pragma unroll
        for (int r = 0; r < 12; ++r) {        // last iteration (k=127), no prefetch
            acc[r] = fmaf(A.x, w[r + 1], acc[r]);
            acc[r] = fmaf(A.y, w[r + 2], acc[r]);
            acc[r] = fmaf(A.z, w[r + 3], acc[r]);
            acc[r] = fmaf(A.w, w[r + 4], acc[r]);
        }
    }
    // Window now holds X[12s+508 .. 12s+524): e_{512+i} = w[4+i].

    // Epilogue: per-lag norms from registers.
    //   q(r) = T(512+r) - T(r),  r = 1..12
    //   T(r)     = sum_{j<r} sq[j]           (prologue squares, f64-summed)
    //   T(512+r) = T512 + sum_{j<r} w[4+j]^2 (end-window squares, f64-summed)
    double qv[12];
    {
        double Thi = T512, Tlo = 0.0;
        #pragma unroll
        for (int r = 1; r <= 12; ++r) {
            float eh = w[3 + r];              // X[12s+512+(r-1)]
            Thi += (double)(eh * eh);
            Tlo += (double)sq[r - 1];
            qv[r - 1] = Thi - Tlo;
        }
    }
    double s1d = __shfl(T512, 0, 16);         // frame sumsq P[512] (lane s=0)

    // Per-lane selection over its 12 lags (fp32, np-like first-max ties).
    float bestv = -1e30f, halfv = -1e30f;
    int bestk = 1 << 30, halfk = 1 << 30;
    {
        float s1 = 1e-9f + sqrtf((float)s1d);
        float s1n = s1 * s1;
        #pragma unroll
        for (int r = 1; r <= 12; ++r) {
            int lag  = 12 * s + r;
            int kidx = lag - 1;               // nccf lag index 0..191
            if (kidx <= 188) {
                float s2 = 1e-9f + sqrtf((float)qv[r - 1]);
                float v  = acc[r - 1] / s1n / (s2 * s2);
                if (kidx >= 5) {
                    if (v > bestv) { bestv = v; bestk = kidx; }
                    if (kidx <= 93 && v > halfv) { halfv = v; halfk = kidx; }
                }
            }
        }
    }

    // 16-lane (max, first-argmax) reduction for both slices.
    #pragma unroll
    for (int off = 8; off >= 1; off >>= 1) {
        float ov = __shfl_xor(bestv, off, 16); int ok = __shfl_xor(bestk, off, 16);
        if (ov > bestv || (ov == bestv && ok < bestk)) { bestv = ov; bestk = ok; }
        float hv = __shfl_xor(halfv, off, 16); int hk = __shfl_xor(halfk, off, 16);
        if (hv > halfv || (hv == halfv && hk < halfk)) { halfv = hv; halfk = hk; }
    }

    if (valid && s == 0) {
        bool m = (halfv > 0.99f * bestv);
        int sel = m ? halfk : bestk;
        idxArr[b * NFRM + gf] = sel + 1;      // = chosen lag
    }
}

// ---------------- Kernel 2: 30-wide median filter + pitch ----------------
__global__ __launch_bounds__(256) void med_kernel(const int* __restrict__ idxArr,
                                                  float* __restrict__ out) {
    int gid = blockIdx.x * 256 + threadIdx.x;
    if (gid >= 8 * OUTW) return;
    int b = gid / OUTW;
    int i = gid - b * OUTW;
    float o = 0.0f;
    if (i < MEDLEN) {
        const int* row = idxArr + b * NFRM;
        int vals[WINL];
        #pragma unroll
        for (int m = 0; m < WINL; ++m) {
            int sIdx = i + m - PADL;          // left pad = repeat idx[0]
            vals[m] = row[sIdx < 0 ? 0 : sIdx];
        }
        int med = vals[0];
        #pragma unroll
        for (int c = 0; c < WINL; ++c) {
            int cl = 0, ce = 0;
            #pragma unroll
            for (int m = 0; m < WINL; ++m) {
                cl += (vals[m] <  vals[c]) ? 1 : 0;
                ce += (vals[m] == vals[c]) ? 1 : 0;
            }
            if (cl <= 14 && 14 < cl + ce) med = vals[c];   // rank-14 = sorted[14]
        }
        o = 16000.0f / (1e-9f + (float)med);
    }
    out[gid] = o;
}

extern "C" void kernel_launch(void* const* d_in, const int* in_sizes, int n_in,
                              void* d_out, int out_size, void* d_ws, size_t ws_size,
                              hipStream_t stream) {
    const float* wav = (const float*)d_in[0];
    float* out = (float*)d_out;
    int* idxArr = (int*)d_ws;                 // 8*1879 ints = 60128 B

    dim3 gB(NBX, 8);                          // 118 x 8 blocks, 16 frames each
    hipLaunchKernelGGL(nccf_kernel, gB, dim3(256), 0, stream, wav, idxArr);

    int total = 8 * OUTW;
    hipLaunchKernelGGL(med_kernel, dim3((total + 255) / 256), dim3(256), 0, stream,
                       idxArr, out);
}